// Round 2
// baseline (517.154 us; speedup 1.0000x reference)
//
#include <hip/hip_runtime.h>
#include <hip/hip_bf16.h>
#include <cstdint>

typedef short short8 __attribute__((ext_vector_type(8)));
typedef __bf16 bf16x8 __attribute__((ext_vector_type(8)));
typedef float float4v __attribute__((ext_vector_type(4)));
typedef float float16v __attribute__((ext_vector_type(16)));

#define NKV 8
#define G 8
#define D 64
#define NH 64
#define BB 2
#define S 1024
#define H 4096
#define MROWS (BB*S)         // 2048
#define NQKV (H + 2*NKV*D)   // 5120

__device__ __forceinline__ unsigned short f2b(float f) {
    union { float f; uint32_t u; } v; v.f = f;
    uint32_t u = v.u;
    uint32_t r = (u + 0x7FFFu + ((u >> 16) & 1u)) >> 16;
    return (unsigned short)r;
}
__device__ __forceinline__ float b2f(unsigned short b) {
    union { float f; uint32_t u; } v; v.u = ((uint32_t)b) << 16;
    return v.f;
}

__device__ __forceinline__ void gload_lds16(const unsigned short* g, unsigned short* l) {
    __builtin_amdgcn_global_load_lds(
        (const __attribute__((address_space(1))) uint32_t*)g,
        (__attribute__((address_space(3))) uint32_t*)l, 16, 0, 0);
}

// ---------------- fused fp32 -> bf16 conversion for all 5 tensors ----------------
__global__ void cvt_all(const float* __restrict__ hs, const float* __restrict__ wq,
                        const float* __restrict__ wk, const float* __restrict__ wv,
                        const float* __restrict__ wd,
                        unsigned short* __restrict__ hs_b, unsigned short* __restrict__ wqkv_b,
                        unsigned short* __restrict__ wd_b) {
    const size_t N0 = (size_t)MROWS * H;      // 8388608  hs
    const size_t N1 = (size_t)H * H;          // 16777216 wq
    const size_t N2 = (size_t)512 * H;        // 2097152  wk
    const size_t N3 = (size_t)512 * H;        // 2097152  wv
    const size_t N4 = (size_t)H * H;          // 16777216 wd
    const size_t total4 = (N0 + N1 + N2 + N3 + N4) / 4;
    size_t i = (size_t)blockIdx.x * blockDim.x + threadIdx.x;
    const size_t stride = (size_t)gridDim.x * blockDim.x;
    for (; i < total4; i += stride) {
        size_t e = i * 4;
        const float* s; unsigned short* d;
        if (e < N0)                { s = hs + e;                  d = hs_b + e; }
        else if (e < N0+N1)        { s = wq + (e-N0);             d = wqkv_b + (e-N0); }
        else if (e < N0+N1+N2)     { s = wk + (e-N0-N1);          d = wqkv_b + N1 + (e-N0-N1); }
        else if (e < N0+N1+N2+N3)  { s = wv + (e-N0-N1-N2);       d = wqkv_b + N1+N2 + (e-N0-N1-N2); }
        else                       { s = wd + (e-N0-N1-N2-N3);    d = wd_b + (e-N0-N1-N2-N3); }
        float4 f = *(const float4*)s;
        ushort4 o;
        o.x = f2b(f.x); o.y = f2b(f.y); o.z = f2b(f.z); o.w = f2b(f.w);
        *(ushort4*)d = o;
    }
}

// ---------------- 8-phase 256x256 NT GEMM (m201-template, plain HIP) ----------------
// C[M,N] = A[M,K] * W[N,K]^T.  512 threads (8 waves, 2Mx4N), BK=64, 2 K-tiles/iter,
// 8 phases/iter, counted vmcnt(6), LDS chunk-XOR swizzle (inverse-applied on global
// source so global_load_lds dest stays linear), setprio around MFMA clusters,
// bijective XCD blockIdx swizzle (nwg % 8 == 0 for both launches).
//
// Region-lifetime discipline (the round-1 bug): a half-region (A-lo/A-hi/B-lo/B-hi
// of a buffer) is re-staged only at phase >= last-read-phase + 1. Read schedule:
// all B fragments read in the tile's first phase (P0/P4); A read in two chunks
// (P0+P2 / P4+P6). Stage slots: P0:A1hi(t+1) P1:B0lo(t+2) P2:B0hi(t+2) P3:A0lo(t+2)
// P4:A0hi(t+2) P5:B1lo(t+3) P6:B1hi(t+3) P7:A1lo(t+3). vmcnt(6) at P3 and P7 ->
// exactly 3 half-stages (6 loads) younger than the tile about to be consumed.
// OUT_MODE 0: bf16 store.  OUT_MODE 1: fp32 unsafeAtomicAdd (K-split; caller memsets C).
#define STAGE_A(BUF, HH, T) { \
    const unsigned short* s_ = Ab + (size_t)((HH) * 128) * K + (T) * 64; \
    unsigned short* d_ = &smem[(BUF) * 32768 + (HH) * 8192 + dst0]; \
    gload_lds16(s_, d_); \
    gload_lds16(s_ + (size_t)64 * K, d_ + 4096); }
#define STAGE_B(BUF, HH, T) { \
    const unsigned short* s_ = Wb + (size_t)((HH) * 128) * K + (T) * 64; \
    unsigned short* d_ = &smem[(BUF) * 32768 + 16384 + (HH) * 8192 + dst0]; \
    gload_lds16(s_, d_); \
    gload_lds16(s_ + (size_t)64 * K, d_ + 4096); }
#define RD_A4(BUF, MOFF) { \
    _Pragma("unroll") \
    for (int m_ = 0; m_ < 4; m_++) { \
      af[m_][0] = *(const bf16x8*)&smem[(BUF) * 32768 + arow0 + ((MOFF) + m_) * 1024 + sl0]; \
      af[m_][1] = *(const bf16x8*)&smem[(BUF) * 32768 + arow0 + ((MOFF) + m_) * 1024 + sl1]; } }
#define RD_B8(BUF) { \
    _Pragma("unroll") \
    for (int n_ = 0; n_ < 4; n_++) { \
      bf[n_][0] = *(const bf16x8*)&smem[(BUF) * 32768 + brow0 + n_ * 1024 + sl0]; \
      bf[n_][1] = *(const bf16x8*)&smem[(BUF) * 32768 + brow0 + n_ * 1024 + sl1]; } }
#define PTAIL() { __builtin_amdgcn_s_barrier(); \
    asm volatile("s_waitcnt lgkmcnt(0)" ::: "memory"); \
    __builtin_amdgcn_sched_barrier(0); }
#define QUAD(MB, NB) { __builtin_amdgcn_s_setprio(1); \
    _Pragma("unroll") \
    for (int s_ = 0; s_ < 2; s_++) \
    _Pragma("unroll") \
    for (int m_ = 0; m_ < 4; m_++) \
    _Pragma("unroll") \
    for (int n_ = 0; n_ < 2; n_++) \
      acc[(MB) + m_][(NB) + n_] = __builtin_amdgcn_mfma_f32_16x16x32_bf16( \
          af[m_][s_], bf[(NB) + n_][s_], acc[(MB) + m_][(NB) + n_], 0, 0, 0); \
    __builtin_amdgcn_s_setprio(0); }
#define EBAR() __builtin_amdgcn_s_barrier();
#define VM6() asm volatile("s_waitcnt vmcnt(6)" ::: "memory");

template <int OUT_MODE>
__global__ __launch_bounds__(512) void gemm8p(
    const unsigned short* __restrict__ A, const unsigned short* __restrict__ W,
    void* __restrict__ Cv, int M, int N, int K, int ksplit) {
    __shared__ unsigned short smem[65536];  // 128 KiB: [buf][A 256x64 | B 256x64]
    const int tid = threadIdx.x;
    const int lane = tid & 63;
    const int w = tid >> 6;
    const int wm = w >> 2, wn = w & 3;
    const int col16 = lane & 15, quad = lane >> 4;

    // bijective XCD swizzle (nwg % 8 == 0): XCD k owns a contiguous strip of tiles
    const int gx = gridDim.x, gy = gridDim.y;
    const int nwg = gx * gy * gridDim.z;
    const int orig = blockIdx.x + gx * (blockIdx.y + gy * blockIdx.z);
    const int swzb = (orig & 7) * (nwg >> 3) + (orig >> 3);
    const int bx = swzb % gx;
    const int rem = swzb / gx;
    const int by = rem % gy, bz = rem / gy;
    const int bm = by << 8, bn = bx << 8;
    const int Kloc = K / ksplit;
    const int k0 = bz * Kloc;
    const int nt = Kloc >> 6;      // 64-wide K tiles
    const int niter = nt >> 1;

    // staging map: thread t -> row t>>3 (+64 for second load), 16B chunk
    // (t&7)^(row&7) (inverse swizzle on the GLOBAL source; LDS dest linear).
    // LDS[row][slot] = global[row][slot ^ (row&7)]
    const int srow = tid >> 3;
    const int csw8 = ((tid & 7) ^ (srow & 7)) * 8;
    const unsigned short* Ab = A + (size_t)(bm + srow) * K + k0 + csw8;
    const unsigned short* Wb = W + (size_t)(bn + srow) * K + k0 + csw8;
    const int dst0 = srow * 64 + (tid & 7) * 8;   // == tid*8 shorts, linear per wave

    // read map: row = base + col16; chunk c -> slot c ^ (row&7)
    const int xk = col16 & 7;
    const int sl0 = (quad ^ xk) * 8;
    const int sl1 = ((quad + 4) ^ xk) * 8;
    const int arow0 = (wm * 128 + col16) * 64;
    const int brow0 = (wn * 64 + col16) * 64 + 16384;

    float4v acc[8][4] = {};
    bf16x8 af[4][2], bf[4][2];

    // prologue: tile0 full (8 loads: B-lo,B-hi,A-lo,A-hi) + tile1 minus A-hi (6 loads)
    STAGE_B(0, 0, 0) STAGE_B(0, 1, 0) STAGE_A(0, 0, 0) STAGE_A(0, 1, 0)
    STAGE_B(1, 0, 1) STAGE_B(1, 1, 1) STAGE_A(1, 0, 1)
    asm volatile("s_waitcnt vmcnt(6)" ::: "memory");
    __builtin_amdgcn_s_barrier();

    for (int i = 0; i < niter; ++i) {
        const int t = i * 2;
        // clamp (not skip) last-iter prefetches: keeps vmcnt counts uniform; clamped
        // writes land only in regions already past their final read.
        const int tc2 = (t + 2 < nt) ? t + 2 : nt - 1;
        const int tc3 = (t + 3 < nt) ? t + 3 : nt - 1;
        // ---- tile t (buf0): phases 0-3 ----
        RD_A4(0, 0) RD_B8(0) STAGE_A(1, 1, t + 1) PTAIL() QUAD(0, 0) EBAR()
        STAGE_B(0, 0, tc2)                        PTAIL() QUAD(0, 2) EBAR()
        RD_A4(0, 4)          STAGE_B(0, 1, tc2)   PTAIL() QUAD(4, 2) EBAR()
        STAGE_A(0, 0, tc2)                        PTAIL() QUAD(4, 0) VM6() EBAR()
        // ---- tile t+1 (buf1): phases 4-7 ----
        RD_A4(1, 0) RD_B8(1) STAGE_A(0, 1, tc2)   PTAIL() QUAD(0, 0) EBAR()
        STAGE_B(1, 0, tc3)                        PTAIL() QUAD(0, 2) EBAR()
        RD_A4(1, 4)          STAGE_B(1, 1, tc3)   PTAIL() QUAD(4, 2) EBAR()
        STAGE_A(1, 0, tc3)                        PTAIL() QUAD(4, 0) VM6() EBAR()
    }

    // epilogue: C/D layout col=lane&15, row=quad*4+reg
#pragma unroll
    for (int mf = 0; mf < 8; mf++) {
        const int gr0 = bm + wm * 128 + mf * 16 + quad * 4;
#pragma unroll
        for (int nf = 0; nf < 4; nf++) {
            const int gc = bn + wn * 64 + nf * 16 + col16;
#pragma unroll
            for (int r = 0; r < 4; r++) {
                if (OUT_MODE == 0)
                    ((unsigned short*)Cv)[(size_t)(gr0 + r) * N + gc] = f2b(acc[mf][nf][r]);
                else
                    unsafeAtomicAdd(&((float*)Cv)[(size_t)(gr0 + r) * N + gc], acc[mf][nf][r]);
            }
        }
    }
}

// ---------------- RoPE + scatter; V written TRANSPOSED [b,kv][d][s] ----------------
__global__ void rope_scatter(const unsigned short* __restrict__ qkv,
                             const float* __restrict__ cosb, const float* __restrict__ sinb,
                             unsigned short* __restrict__ qa, unsigned short* __restrict__ ka,
                             unsigned short* __restrict__ vt) {
    int idx = blockIdx.x * blockDim.x + threadIdx.x;
    const int total = MROWS * NQKV;
    const int stride = gridDim.x * blockDim.x;
    for (; idx < total; idx += stride) {
        int row = idx / NQKV, o = idx - row * NQKV;
        int b = row >> 10, s = row & 1023;
        float x = b2f(qkv[idx]);
        if (o < H) {
            int kv = o >> 9, g = (o >> 6) & 7, d = o & 63;
            int po = (d < 32) ? idx + 32 : idx - 32;
            float partner = b2f(qkv[po]);
            float rot = (d < 32) ? -partner : partner;
            float y = x * cosb[s * 64 + d] + rot * sinb[s * 64 + d];
            int h = b * 64 + kv * 8 + g;
            qa[(size_t)h * (S * D) + s * 64 + d] = f2b(y);
        } else if (o < H + 512) {
            int o2 = o - H;
            int kv = o2 >> 6, d = o2 & 63;
            int po = (d < 32) ? idx + 32 : idx - 32;
            float partner = b2f(qkv[po]);
            float rot = (d < 32) ? -partner : partner;
            float y = x * cosb[s * 64 + d] + rot * sinb[s * 64 + d];
            ka[(size_t)(b * NKV + kv) * (S * D) + s * 64 + d] = f2b(y);
        } else {
            int o2 = o - H - 512;
            int kv = o2 >> 6, d = o2 & 63;
            vt[(size_t)(b * NKV + kv) * (D * S) + (size_t)d * S + s] = qkv[idx];
        }
    }
}

// ---------------- Flash attention, pair-balanced, 2 query heads per block ----------------
__global__ __launch_bounds__(256) void attn_kernel(
    const unsigned short* __restrict__ qa, const unsigned short* __restrict__ ka,
    const unsigned short* __restrict__ vt, unsigned short* __restrict__ out) {
    __shared__ unsigned short Ks[64 * 72];
    __shared__ unsigned short Vs[64 * 72];   // V^T tile: [d][key]
    __shared__ unsigned short Ps[4 * 16 * 72];
    const int p = blockIdx.x;
    const int yy = blockIdx.y;
    const int b = yy >> 5, kvh = (yy >> 2) & 7, gp = yy & 3;
    const int h0 = b * 64 + kvh * 8 + gp * 2;
    const int tid = threadIdx.x, w = tid >> 6, lane = tid & 63;
    const int col = lane & 15, quad = lane >> 4;
    const unsigned short* Kg = ka + (size_t)(b * NKV + kvh) * (S * D);
    const unsigned short* Vg = vt + (size_t)(b * NKV + kvh) * (D * S);
    const int srow = tid >> 3, scc = (tid & 7) * 8;
    float4v zero4 = {0.f, 0.f, 0.f, 0.f};
    const float SC2 = 0.125f * 1.44269504089f;  // fold 1/sqrt(D) and log2(e): exp2 domain

#pragma unroll
    for (int part = 0; part < 2; part++) {
        const int qt = part ? (15 - p) : p;
        const int qb = qt * 64;

        bf16x8 aq[2][2];
#pragma unroll
        for (int hd = 0; hd < 2; hd++)
#pragma unroll
            for (int c = 0; c < 2; c++)
                aq[hd][c] = *(const bf16x8*)&qa[(size_t)(h0 + hd) * (S * D) + (size_t)qb * D
                                               + (w * 16 + col) * 64 + c * 32 + quad * 8];

        float m_run[2][4], l_run[2][4];
        float4v o_acc[2][4];
#pragma unroll
        for (int hd = 0; hd < 2; hd++) {
#pragma unroll
            for (int r = 0; r < 4; r++) { m_run[hd][r] = -1e30f; l_run[hd][r] = 0.f; }
#pragma unroll
            for (int dg = 0; dg < 4; dg++) o_acc[hd][dg] = zero4;
        }

        for (int kt = 0; kt <= qt; kt++) {
            const int kb = kt * 64;
            __syncthreads();
            *(short8*)&Ks[srow * 72 + scc]        = *(const short8*)&Kg[(kb + srow) * 64 + scc];
            *(short8*)&Ks[(srow + 32) * 72 + scc] = *(const short8*)&Kg[(kb + srow + 32) * 64 + scc];
            *(short8*)&Vs[srow * 72 + scc]        = *(const short8*)&Vg[(size_t)srow * S + kb + scc];
            *(short8*)&Vs[(srow + 32) * 72 + scc] = *(const short8*)&Vg[(size_t)(srow + 32) * S + kb + scc];
            __syncthreads();

#pragma unroll
            for (int hd = 0; hd < 2; hd++) {
                float4v sc[4];
#pragma unroll
                for (int n16 = 0; n16 < 4; n16++) {
                    bf16x8 bk0 = *(const bf16x8*)&Ks[(n16 * 16 + col) * 72 + quad * 8];
                    bf16x8 bk1 = *(const bf16x8*)&Ks[(n16 * 16 + col) * 72 + 32 + quad * 8];
                    float4v a = __builtin_amdgcn_mfma_f32_16x16x32_bf16(aq[hd][0], bk0, zero4, 0, 0, 0);
                    sc[n16] = __builtin_amdgcn_mfma_f32_16x16x32_bf16(aq[hd][1], bk1, a, 0, 0, 0);
                }
#pragma unroll
                for (int n16 = 0; n16 < 4; n16++) {
                    int key = kb + n16 * 16 + col;
#pragma unroll
                    for (int r = 0; r < 4; r++) {
                        int qrow = qb + w * 16 + quad * 4 + r;
                        float sv = sc[n16][r] * SC2;
                        sc[n16][r] = (key <= qrow) ? sv : -1e30f;
                    }
                }
#pragma unroll
                for (int r = 0; r < 4; r++) {
                    float mx = fmaxf(fmaxf(sc[0][r], sc[1][r]), fmaxf(sc[2][r], sc[3][r]));
#pragma unroll
                    for (int off = 1; off < 16; off <<= 1) mx = fmaxf(mx, __shfl_xor(mx, off));
                    float mnew = fmaxf(m_run[hd][r], mx);
                    float alpha = __builtin_amdgcn_exp2f(m_run[hd][r] - mnew);
                    float rsum = 0.f;
#pragma unroll
                    for (int n16 = 0; n16 < 4; n16++) {
                        float pr = __builtin_amdgcn_exp2f(sc[n16][r] - mnew);
                        sc[n16][r] = pr;
                        rsum += pr;
                    }
#pragma unroll
                    for (int off = 1; off < 16; off <<= 1) rsum += __shfl_xor(rsum, off);
                    l_run[hd][r] = l_run[hd][r] * alpha + rsum;
                    m_run[hd][r] = mnew;
#pragma unroll
                    for (int dg = 0; dg < 4; dg++) o_acc[hd][dg][r] *= alpha;
                }
#pragma unroll
                for (int n16 = 0; n16 < 4; n16++)
#pragma unroll
                    for (int r = 0; r < 4; r++)
                        Ps[w * 1152 + (quad * 4 + r) * 72 + n16 * 16 + col] = f2b(sc[n16][r]);
                bf16x8 ap[2];
#pragma unroll
                for (int c = 0; c < 2; c++)
                    ap[c] = *(const bf16x8*)&Ps[w * 1152 + col * 72 + c * 32 + quad * 8];
#pragma unroll
                for (int dg = 0; dg < 4; dg++) {
                    bf16x8 bv0 = *(const bf16x8*)&Vs[(dg * 16 + col) * 72 + quad * 8];
                    bf16x8 bv1 = *(const bf16x8*)&Vs[(dg * 16 + col) * 72 + 32 + quad * 8];
                    float4v t = __builtin_amdgcn_mfma_f32_16x16x32_bf16(ap[0], bv0, o_acc[hd][dg], 0, 0, 0);
                    o_acc[hd][dg] = __builtin_amdgcn_mfma_f32_16x16x32_bf16(ap[1], bv1, t, 0, 0, 0);
                }
            }
        }
#pragma unroll
        for (int hd = 0; hd < 2; hd++) {
            const int hcol = ((h0 + hd) & 63) * 64;
#pragma unroll
            for (int r = 0; r < 4; r++) {
                float inv = 1.f / l_run[hd][r];
                int grow = b * S + qb + w * 16 + quad * 4 + r;
#pragma unroll
                for (int dg = 0; dg < 4; dg++)
                    out[(size_t)grow * H + hcol + dg * 16 + col] = f2b(o_acc[hd][dg][r] * inv);
            }
        }
    }
}

extern "C" void kernel_launch(void* const* d_in, const int* in_sizes, int n_in,
                              void* d_out, int out_size, void* d_ws, size_t ws_size,
                              hipStream_t stream) {
    const float* hs   = (const float*)d_in[0];
    // d_in[1] alibi, d_in[2] attention_mask: unused by reference (zeros)
    const float* cosb = (const float*)d_in[3];
    const float* sinb = (const float*)d_in[4];
    const float* wq   = (const float*)d_in[5];
    const float* wk   = (const float*)d_in[6];
    const float* wv   = (const float*)d_in[7];
    const float* wd   = (const float*)d_in[8];

    char* p = (char*)d_ws;
    auto alloc = [&](size_t bytes) { char* r = p; p += (bytes + 255) & ~(size_t)255; return r; };
    unsigned short* wqkv_b = (unsigned short*)alloc((size_t)NQKV * H * 2);
    unsigned short* wd_b   = (unsigned short*)alloc((size_t)H * H * 2);
    unsigned short* qkv    = (unsigned short*)alloc((size_t)MROWS * NQKV * 2);
    unsigned short* qa     = (unsigned short*)alloc((size_t)BB * NH * S * D * 2);
    unsigned short* ka     = (unsigned short*)alloc((size_t)BB * NKV * S * D * 2);
    unsigned short* vt     = (unsigned short*)alloc((size_t)BB * NKV * S * D * 2);
    unsigned short* hs_b   = (unsigned short*)alloc((size_t)MROWS * H * 2);
    unsigned short* ao     = hs_b;  // alias: hs_b consumed by GEMM1 before attn writes ao

    // GEMM2 is K-split x2 with fp32 atomics -> output must start zeroed
    hipMemsetAsync(d_out, 0, (size_t)MROWS * H * sizeof(float), stream);

    cvt_all<<<4096, 256, 0, stream>>>(hs, wq, wk, wv, wd, hs_b, wqkv_b, wd_b);

    // GEMM1: 256x256 tiles -> 20x8 = 160 blocks (nwg%8==0), ksplit=1, bf16 out
    gemm8p<0><<<dim3(NQKV / 256, MROWS / 256, 1), 512, 0, stream>>>(
        hs_b, wqkv_b, qkv, MROWS, NQKV, H, 1);
    rope_scatter<<<4096, 256, 0, stream>>>(qkv, cosb, sinb, qa, ka, vt);
    attn_kernel<<<dim3(8, 64), 256, 0, stream>>>(qa, ka, vt, ao);
    // GEMM2: 256x256 tiles, K-split 2 -> 16x8x2 = 256 blocks (1/CU), fp32 atomicAdd
    gemm8p<1><<<dim3(H / 256, MROWS / 256, 2), 512, 0, stream>>>(
        ao, wd_b, d_out, MROWS, H, H, 2);
}

// Round 3
// 486.297 us; speedup vs baseline: 1.0635x; 1.0635x over previous
//
#include <hip/hip_runtime.h>
#include <hip/hip_bf16.h>
#include <cstdint>

typedef short short8 __attribute__((ext_vector_type(8)));
typedef __bf16 bf16x8 __attribute__((ext_vector_type(8)));
typedef float float4v __attribute__((ext_vector_type(4)));
typedef float float16v __attribute__((ext_vector_type(16)));

#define NKV 8
#define G 8
#define D 64
#define NH 64
#define BB 2
#define S 1024
#define H 4096
#define MROWS (BB*S)         // 2048
#define NQKV (H + 2*NKV*D)   // 5120

__device__ __forceinline__ unsigned short f2b(float f) {
    union { float f; uint32_t u; } v; v.f = f;
    uint32_t u = v.u;
    uint32_t r = (u + 0x7FFFu + ((u >> 16) & 1u)) >> 16;
    return (unsigned short)r;
}
__device__ __forceinline__ float b2f(unsigned short b) {
    union { float f; uint32_t u; } v; v.u = ((uint32_t)b) << 16;
    return v.f;
}

__device__ __forceinline__ void gload_lds16(const unsigned short* g, unsigned short* l) {
    __builtin_amdgcn_global_load_lds(
        (const __attribute__((address_space(1))) uint32_t*)g,
        (__attribute__((address_space(3))) uint32_t*)l, 16, 0, 0);
}

// ---------------- fused fp32 -> bf16 conversion for all 5 tensors ----------------
__global__ void cvt_all(const float* __restrict__ hs, const float* __restrict__ wq,
                        const float* __restrict__ wk, const float* __restrict__ wv,
                        const float* __restrict__ wd,
                        unsigned short* __restrict__ hs_b, unsigned short* __restrict__ wqkv_b,
                        unsigned short* __restrict__ wd_b) {
    const size_t N0 = (size_t)MROWS * H;      // 8388608  hs
    const size_t N1 = (size_t)H * H;          // 16777216 wq
    const size_t N2 = (size_t)512 * H;        // 2097152  wk
    const size_t N3 = (size_t)512 * H;        // 2097152  wv
    const size_t N4 = (size_t)H * H;          // 16777216 wd
    const size_t total4 = (N0 + N1 + N2 + N3 + N4) / 4;
    size_t i = (size_t)blockIdx.x * blockDim.x + threadIdx.x;
    const size_t stride = (size_t)gridDim.x * blockDim.x;
    for (; i < total4; i += stride) {
        size_t e = i * 4;
        const float* s; unsigned short* d;
        if (e < N0)                { s = hs + e;                  d = hs_b + e; }
        else if (e < N0+N1)        { s = wq + (e-N0);             d = wqkv_b + (e-N0); }
        else if (e < N0+N1+N2)     { s = wk + (e-N0-N1);          d = wqkv_b + N1 + (e-N0-N1); }
        else if (e < N0+N1+N2+N3)  { s = wv + (e-N0-N1-N2);       d = wqkv_b + N1+N2 + (e-N0-N1-N2); }
        else                       { s = wd + (e-N0-N1-N2-N3);    d = wd_b + (e-N0-N1-N2-N3); }
        float4 f = *(const float4*)s;
        ushort4 o;
        o.x = f2b(f.x); o.y = f2b(f.y); o.z = f2b(f.z); o.w = f2b(f.w);
        *(ushort4*)d = o;
    }
}

// ---------------- NT GEMM: C[M,N] = A[M,K] * W[N,K]^T ----------------
// Proven round-0 structure: 128x128 tile, BK=32, 4 waves (2x2 of 64x64),
// mfma_f32_32x32x16_bf16 (2x2 of 32x32 per wave), global_load_lds width=16 staging,
// XOR chunk swizzle, pointer-bumped K loop. 114.7 us measured at both shapes.
template <bool BF16_OUT>
__global__ __launch_bounds__(256) void gemm_nt(
    const unsigned short* __restrict__ A, const unsigned short* __restrict__ W,
    void* __restrict__ Cv, int M, int N, int K) {
    __shared__ unsigned short As[128 * 32];
    __shared__ unsigned short Bs[128 * 32];
    const int bm = blockIdx.y * 128, bn = blockIdx.x * 128;
    const int tid = threadIdx.x;
    const int w = tid >> 6, lane = tid & 63;
    const int n32 = lane & 31, khalf = lane >> 5;
    const int wm = (w & 1) * 64, wn = (w >> 1) * 64;

    const int r0 = tid >> 2;
    const int c0 = (tid & 3) ^ ((r0 >> 2) & 3);
    const unsigned short* pA0 = A + (size_t)(bm + r0) * K + c0 * 8;
    const unsigned short* pA1 = A + (size_t)(bm + r0 + 64) * K + c0 * 8;
    const unsigned short* pW0 = W + (size_t)(bn + r0) * K + c0 * 8;
    const unsigned short* pW1 = W + (size_t)(bn + r0 + 64) * K + c0 * 8;
    unsigned short* Asl0 = As + tid * 8;
    unsigned short* Asl1 = As + 2048 + tid * 8;
    unsigned short* Bsl0 = Bs + tid * 8;
    unsigned short* Bsl1 = Bs + 2048 + tid * 8;

    const unsigned short* aP[2][2];
    const unsigned short* bP[2][2];
#pragma unroll
    for (int g = 0; g < 2; g++)
#pragma unroll
        for (int s = 0; s < 2; s++) {
            int cp = ((s << 1) | khalf) ^ ((n32 >> 2) & 3);
            aP[g][s] = &As[(wm + g * 32 + n32) * 32 + cp * 8];
            bP[g][s] = &Bs[(wn + g * 32 + n32) * 32 + cp * 8];
        }

    float16v acc[2][2] = {};

    const int iters = K >> 5;
    for (int it = 0; it < iters; ++it) {
        __syncthreads();
        gload_lds16(pA0, Asl0);
        gload_lds16(pA1, Asl1);
        gload_lds16(pW0, Bsl0);
        gload_lds16(pW1, Bsl1);
        pA0 += 32; pA1 += 32; pW0 += 32; pW1 += 32;
        __syncthreads();
        bf16x8 af[2][2], bf[2][2];
#pragma unroll
        for (int g = 0; g < 2; g++)
#pragma unroll
            for (int s = 0; s < 2; s++) {
                af[g][s] = *(const bf16x8*)aP[g][s];
                bf[g][s] = *(const bf16x8*)bP[g][s];
            }
#pragma unroll
        for (int s = 0; s < 2; s++)
#pragma unroll
            for (int mg = 0; mg < 2; mg++)
#pragma unroll
                for (int ng = 0; ng < 2; ng++)
                    acc[mg][ng] = __builtin_amdgcn_mfma_f32_32x32x16_bf16(
                        af[mg][s], bf[ng][s], acc[mg][ng], 0, 0, 0);
    }

    // epilogue: C/D layout (verified): col = lane&31, row = (reg&3) + 8*(reg>>2) + 4*(lane>>5)
#pragma unroll
    for (int mg = 0; mg < 2; mg++) {
#pragma unroll
        for (int ng = 0; ng < 2; ng++) {
            int gcol = bn + wn + ng * 32 + n32;
#pragma unroll
            for (int reg = 0; reg < 16; reg++) {
                int grow = bm + wm + mg * 32 + (reg & 3) + 8 * (reg >> 2) + 4 * khalf;
                if (BF16_OUT)
                    ((unsigned short*)Cv)[(size_t)grow * N + gcol] = f2b(acc[mg][ng][reg]);
                else
                    ((float*)Cv)[(size_t)grow * N + gcol] = acc[mg][ng][reg];
            }
        }
    }
}

// ---------------- RoPE + scatter; V written TRANSPOSED [b,kv][d][s] ----------------
__global__ void rope_scatter(const unsigned short* __restrict__ qkv,
                             const float* __restrict__ cosb, const float* __restrict__ sinb,
                             unsigned short* __restrict__ qa, unsigned short* __restrict__ ka,
                             unsigned short* __restrict__ vt) {
    int idx = blockIdx.x * blockDim.x + threadIdx.x;
    const int total = MROWS * NQKV;
    const int stride = gridDim.x * blockDim.x;
    for (; idx < total; idx += stride) {
        int row = idx / NQKV, o = idx - row * NQKV;
        int b = row >> 10, s = row & 1023;
        float x = b2f(qkv[idx]);
        if (o < H) {
            int kv = o >> 9, g = (o >> 6) & 7, d = o & 63;
            int po = (d < 32) ? idx + 32 : idx - 32;
            float partner = b2f(qkv[po]);
            float rot = (d < 32) ? -partner : partner;
            float y = x * cosb[s * 64 + d] + rot * sinb[s * 64 + d];
            int h = b * 64 + kv * 8 + g;
            qa[(size_t)h * (S * D) + s * 64 + d] = f2b(y);
        } else if (o < H + 512) {
            int o2 = o - H;
            int kv = o2 >> 6, d = o2 & 63;
            int po = (d < 32) ? idx + 32 : idx - 32;
            float partner = b2f(qkv[po]);
            float rot = (d < 32) ? -partner : partner;
            float y = x * cosb[s * 64 + d] + rot * sinb[s * 64 + d];
            ka[(size_t)(b * NKV + kv) * (S * D) + s * 64 + d] = f2b(y);
        } else {
            int o2 = o - H - 512;
            int kv = o2 >> 6, d = o2 & 63;
            vt[(size_t)(b * NKV + kv) * (D * S) + (size_t)d * S + s] = qkv[idx];
        }
    }
}

// ---------------- Flash attention, pair-balanced, 2 query heads per block ----------------
// Change vs round-0: K/V LDS staging DROPPED (K/V are 128KB/head-pair, shared by 32
// blocks -> L2-resident; staged reads were address-identical to direct global reads).
// This removes BOTH per-K-tile __syncthreads -> waves run desynchronized. K/V frags
// hoisted to registers once per K-tile, reused by both heads. setprio(1) wraps the
// MFMA clusters (applies now that waves are at different phases).
__global__ __launch_bounds__(256) void attn_kernel(
    const unsigned short* __restrict__ qa, const unsigned short* __restrict__ ka,
    const unsigned short* __restrict__ vt, unsigned short* __restrict__ out) {
    __shared__ unsigned short Ps[4 * 16 * 72];   // wave-private P round-trip only
    const int p = blockIdx.x;
    const int yy = blockIdx.y;
    const int b = yy >> 5, kvh = (yy >> 2) & 7, gp = yy & 3;
    const int h0 = b * 64 + kvh * 8 + gp * 2;
    const int tid = threadIdx.x, w = tid >> 6, lane = tid & 63;
    const int col = lane & 15, quad = lane >> 4;
    const unsigned short* Kg = ka + (size_t)(b * NKV + kvh) * (S * D);
    const unsigned short* Vg = vt + (size_t)(b * NKV + kvh) * (D * S);
    float4v zero4 = {0.f, 0.f, 0.f, 0.f};
    const float SC2 = 0.125f * 1.44269504089f;  // fold 1/sqrt(D) and log2(e): exp2 domain

#pragma unroll
    for (int part = 0; part < 2; part++) {
        const int qt = part ? (15 - p) : p;
        const int qb = qt * 64;

        bf16x8 aq[2][2];
#pragma unroll
        for (int hd = 0; hd < 2; hd++)
#pragma unroll
            for (int c = 0; c < 2; c++)
                aq[hd][c] = *(const bf16x8*)&qa[(size_t)(h0 + hd) * (S * D) + (size_t)qb * D
                                               + (w * 16 + col) * 64 + c * 32 + quad * 8];

        float m_run[2][4], l_run[2][4];
        float4v o_acc[2][4];
#pragma unroll
        for (int hd = 0; hd < 2; hd++) {
#pragma unroll
            for (int r = 0; r < 4; r++) { m_run[hd][r] = -1e30f; l_run[hd][r] = 0.f; }
#pragma unroll
            for (int dg = 0; dg < 4; dg++) o_acc[hd][dg] = zero4;
        }

        for (int kt = 0; kt <= qt; kt++) {
            const int kb = kt * 64;
            // K/V fragments direct from global (L2-hot), once per K-tile, both heads reuse
            bf16x8 bk[4][2], bv[4][2];
#pragma unroll
            for (int n16 = 0; n16 < 4; n16++) {
                const unsigned short* kr = &Kg[(size_t)(kb + n16 * 16 + col) * 64 + quad * 8];
                bk[n16][0] = *(const bf16x8*)kr;
                bk[n16][1] = *(const bf16x8*)(kr + 32);
            }
#pragma unroll
            for (int dg = 0; dg < 4; dg++) {
                const unsigned short* vr = &Vg[(size_t)(dg * 16 + col) * S + kb + quad * 8];
                bv[dg][0] = *(const bf16x8*)vr;
                bv[dg][1] = *(const bf16x8*)(vr + 32);
            }

#pragma unroll
            for (int hd = 0; hd < 2; hd++) {
                float4v sc[4];
                __builtin_amdgcn_s_setprio(1);
#pragma unroll
                for (int n16 = 0; n16 < 4; n16++) {
                    float4v a = __builtin_amdgcn_mfma_f32_16x16x32_bf16(aq[hd][0], bk[n16][0], zero4, 0, 0, 0);
                    sc[n16] = __builtin_amdgcn_mfma_f32_16x16x32_bf16(aq[hd][1], bk[n16][1], a, 0, 0, 0);
                }
                __builtin_amdgcn_s_setprio(0);
#pragma unroll
                for (int n16 = 0; n16 < 4; n16++) {
                    int key = kb + n16 * 16 + col;
#pragma unroll
                    for (int r = 0; r < 4; r++) {
                        int qrow = qb + w * 16 + quad * 4 + r;
                        float sv = sc[n16][r] * SC2;
                        sc[n16][r] = (key <= qrow) ? sv : -1e30f;
                    }
                }
#pragma unroll
                for (int r = 0; r < 4; r++) {
                    float mx = fmaxf(fmaxf(sc[0][r], sc[1][r]), fmaxf(sc[2][r], sc[3][r]));
#pragma unroll
                    for (int off = 1; off < 16; off <<= 1) mx = fmaxf(mx, __shfl_xor(mx, off));
                    float mnew = fmaxf(m_run[hd][r], mx);
                    float alpha = __builtin_amdgcn_exp2f(m_run[hd][r] - mnew);
                    float rsum = 0.f;
#pragma unroll
                    for (int n16 = 0; n16 < 4; n16++) {
                        float pr = __builtin_amdgcn_exp2f(sc[n16][r] - mnew);
                        sc[n16][r] = pr;
                        rsum += pr;
                    }
#pragma unroll
                    for (int off = 1; off < 16; off <<= 1) rsum += __shfl_xor(rsum, off);
                    l_run[hd][r] = l_run[hd][r] * alpha + rsum;
                    m_run[hd][r] = mnew;
#pragma unroll
                    for (int dg = 0; dg < 4; dg++) o_acc[hd][dg][r] *= alpha;
                }
                // P (C/D layout) -> wave-private LDS, no barrier
#pragma unroll
                for (int n16 = 0; n16 < 4; n16++)
#pragma unroll
                    for (int r = 0; r < 4; r++)
                        Ps[w * 1152 + (quad * 4 + r) * 72 + n16 * 16 + col] = f2b(sc[n16][r]);
                bf16x8 ap[2];
#pragma unroll
                for (int c = 0; c < 2; c++)
                    ap[c] = *(const bf16x8*)&Ps[w * 1152 + col * 72 + c * 32 + quad * 8];
                __builtin_amdgcn_s_setprio(1);
#pragma unroll
                for (int dg = 0; dg < 4; dg++) {
                    float4v t = __builtin_amdgcn_mfma_f32_16x16x32_bf16(ap[0], bv[dg][0], o_acc[hd][dg], 0, 0, 0);
                    o_acc[hd][dg] = __builtin_amdgcn_mfma_f32_16x16x32_bf16(ap[1], bv[dg][1], t, 0, 0, 0);
                }
                __builtin_amdgcn_s_setprio(0);
            }
        }
#pragma unroll
        for (int hd = 0; hd < 2; hd++) {
            const int hcol = ((h0 + hd) & 63) * 64;
#pragma unroll
            for (int r = 0; r < 4; r++) {
                float inv = 1.f / l_run[hd][r];
                int grow = b * S + qb + w * 16 + quad * 4 + r;
#pragma unroll
                for (int dg = 0; dg < 4; dg++)
                    out[(size_t)grow * H + hcol + dg * 16 + col] = f2b(o_acc[hd][dg][r] * inv);
            }
        }
    }
}

extern "C" void kernel_launch(void* const* d_in, const int* in_sizes, int n_in,
                              void* d_out, int out_size, void* d_ws, size_t ws_size,
                              hipStream_t stream) {
    const float* hs   = (const float*)d_in[0];
    // d_in[1] alibi, d_in[2] attention_mask: unused by reference (zeros)
    const float* cosb = (const float*)d_in[3];
    const float* sinb = (const float*)d_in[4];
    const float* wq   = (const float*)d_in[5];
    const float* wk   = (const float*)d_in[6];
    const float* wv   = (const float*)d_in[7];
    const float* wd   = (const float*)d_in[8];

    char* p = (char*)d_ws;
    auto alloc = [&](size_t bytes) { char* r = p; p += (bytes + 255) & ~(size_t)255; return r; };
    unsigned short* wqkv_b = (unsigned short*)alloc((size_t)NQKV * H * 2);
    unsigned short* wd_b   = (unsigned short*)alloc((size_t)H * H * 2);
    unsigned short* qkv    = (unsigned short*)alloc((size_t)MROWS * NQKV * 2);
    unsigned short* qa     = (unsigned short*)alloc((size_t)BB * NH * S * D * 2);
    unsigned short* ka     = (unsigned short*)alloc((size_t)BB * NKV * S * D * 2);
    unsigned short* vt     = (unsigned short*)alloc((size_t)BB * NKV * S * D * 2);
    unsigned short* hs_b   = (unsigned short*)alloc((size_t)MROWS * H * 2);
    unsigned short* ao     = hs_b;  // alias: hs_b consumed by GEMM1 before attn writes ao

    cvt_all<<<4096, 256, 0, stream>>>(hs, wq, wk, wv, wd, hs_b, wqkv_b, wd_b);

    gemm_nt<true><<<dim3(NQKV / 128, MROWS / 128), 256, 0, stream>>>(hs_b, wqkv_b, qkv, MROWS, NQKV, H);
    rope_scatter<<<4096, 256, 0, stream>>>(qkv, cosb, sinb, qa, ka, vt);
    attn_kernel<<<dim3(8, 64), 256, 0, stream>>>(qa, ka, vt, ao);
    gemm_nt<false><<<dim3(H / 128, MROWS / 128), 256, 0, stream>>>(ao, wd_b, d_out, MROWS, H, H);
}

// Round 5
// 462.241 us; speedup vs baseline: 1.1188x; 1.0520x over previous
//
#include <hip/hip_runtime.h>
#include <hip/hip_bf16.h>
#include <cstdint>

typedef short short8 __attribute__((ext_vector_type(8)));
typedef __bf16 bf16x8 __attribute__((ext_vector_type(8)));
typedef float float4v __attribute__((ext_vector_type(4)));
typedef float float16v __attribute__((ext_vector_type(16)));

#define NKV 8
#define G 8
#define D 64
#define NH 64
#define BB 2
#define S 1024
#define H 4096
#define MROWS (BB*S)         // 2048
#define NQKV (H + 2*NKV*D)   // 5120

__device__ __forceinline__ unsigned short f2b(float f) {
    union { float f; uint32_t u; } v; v.f = f;
    uint32_t u = v.u;
    uint32_t r = (u + 0x7FFFu + ((u >> 16) & 1u)) >> 16;
    return (unsigned short)r;
}
__device__ __forceinline__ float b2f(unsigned short b) {
    union { float f; uint32_t u; } v; v.u = ((uint32_t)b) << 16;
    return v.f;
}

__device__ __forceinline__ void gload_lds16(const unsigned short* g, unsigned short* l) {
    __builtin_amdgcn_global_load_lds(
        (const __attribute__((address_space(1))) uint32_t*)g,
        (__attribute__((address_space(3))) uint32_t*)l, 16, 0, 0);
}

// ---------------- fused fp32 -> bf16 conversion for all 5 tensors ----------------
__global__ void cvt_all(const float* __restrict__ hs, const float* __restrict__ wq,
                        const float* __restrict__ wk, const float* __restrict__ wv,
                        const float* __restrict__ wd,
                        unsigned short* __restrict__ hs_b, unsigned short* __restrict__ wqkv_b,
                        unsigned short* __restrict__ wd_b) {
    const size_t N0 = (size_t)MROWS * H;      // 8388608  hs
    const size_t N1 = (size_t)H * H;          // 16777216 wq
    const size_t N2 = (size_t)512 * H;        // 2097152  wk
    const size_t N3 = (size_t)512 * H;        // 2097152  wv
    const size_t N4 = (size_t)H * H;          // 16777216 wd
    const size_t total4 = (N0 + N1 + N2 + N3 + N4) / 4;
    size_t i = (size_t)blockIdx.x * blockDim.x + threadIdx.x;
    const size_t stride = (size_t)gridDim.x * blockDim.x;
    for (; i < total4; i += stride) {
        size_t e = i * 4;
        const float* s; unsigned short* d;
        if (e < N0)                { s = hs + e;                  d = hs_b + e; }
        else if (e < N0+N1)        { s = wq + (e-N0);             d = wqkv_b + (e-N0); }
        else if (e < N0+N1+N2)     { s = wk + (e-N0-N1);          d = wqkv_b + N1 + (e-N0-N1); }
        else if (e < N0+N1+N2+N3)  { s = wv + (e-N0-N1-N2);       d = wqkv_b + N1+N2 + (e-N0-N1-N2); }
        else                       { s = wd + (e-N0-N1-N2-N3);    d = wd_b + (e-N0-N1-N2-N3); }
        float4 f = *(const float4*)s;
        ushort4 o;
        o.x = f2b(f.x); o.y = f2b(f.y); o.z = f2b(f.z); o.w = f2b(f.w);
        *(ushort4*)d = o;
    }
}

// ---------------- NT GEMM: C[M,N] = A[M,K] * W[N,K]^T ----------------
// Proven structure: 128x128 tile, BK=32, 4 waves (2x2 of 64x64),
// mfma_f32_32x32x16_bf16 (2x2 of 32x32 per wave), global_load_lds width=16 staging,
// XOR chunk swizzle, pointer-bumped K loop.
// MODE 0: plain fp32 C store (GEMM2).
// MODE 1: fused QKV epilogue (GEMM1): per-wave 64-col window == one head's d range.
//   RoPE partner of acc[mg][0][reg] (d=n32) is acc[mg][1][reg] (d=n32+32): same lane,
//   same reg -> no shuffles. Q cols [0,4096) -> qa, K cols [4096,4608) -> ka (both
//   coalesced); V cols [4608,5120) -> vt[d][s] via in-LDS block transpose.
template <int MODE>
__global__ __launch_bounds__(256) void gemm_nt(
    const unsigned short* __restrict__ A, const unsigned short* __restrict__ W,
    void* __restrict__ Cv, int M, int N, int K,
    const float* __restrict__ cosb, const float* __restrict__ sinb,
    unsigned short* __restrict__ qa, unsigned short* __restrict__ ka,
    unsigned short* __restrict__ vt) {
    __shared__ unsigned short sh[17408];  // As | Bs; reused as 128x136 V-transpose tile
    unsigned short* As = sh;
    unsigned short* Bs = sh + 4096;
    const int bm = blockIdx.y * 128, bn = blockIdx.x * 128;
    const int tid = threadIdx.x;
    const int w = tid >> 6, lane = tid & 63;
    const int n32 = lane & 31, khalf = lane >> 5;
    const int wm = (w & 1) * 64, wn = (w >> 1) * 64;

    const int r0 = tid >> 2;
    const int c0 = (tid & 3) ^ ((r0 >> 2) & 3);
    const unsigned short* pA0 = A + (size_t)(bm + r0) * K + c0 * 8;
    const unsigned short* pA1 = A + (size_t)(bm + r0 + 64) * K + c0 * 8;
    const unsigned short* pW0 = W + (size_t)(bn + r0) * K + c0 * 8;
    const unsigned short* pW1 = W + (size_t)(bn + r0 + 64) * K + c0 * 8;
    unsigned short* Asl0 = As + tid * 8;
    unsigned short* Asl1 = As + 2048 + tid * 8;
    unsigned short* Bsl0 = Bs + tid * 8;
    unsigned short* Bsl1 = Bs + 2048 + tid * 8;

    const unsigned short* aP[2][2];
    const unsigned short* bP[2][2];
#pragma unroll
    for (int g = 0; g < 2; g++)
#pragma unroll
        for (int s = 0; s < 2; s++) {
            int cp = ((s << 1) | khalf) ^ ((n32 >> 2) & 3);
            aP[g][s] = &As[(wm + g * 32 + n32) * 32 + cp * 8];
            bP[g][s] = &Bs[(wn + g * 32 + n32) * 32 + cp * 8];
        }

    float16v acc[2][2] = {};

    const int iters = K >> 5;
    for (int it = 0; it < iters; ++it) {
        __syncthreads();
        gload_lds16(pA0, Asl0);
        gload_lds16(pA1, Asl1);
        gload_lds16(pW0, Bsl0);
        gload_lds16(pW1, Bsl1);
        pA0 += 32; pA1 += 32; pW0 += 32; pW1 += 32;
        __syncthreads();
        bf16x8 af[2][2], bf[2][2];
#pragma unroll
        for (int g = 0; g < 2; g++)
#pragma unroll
            for (int s = 0; s < 2; s++) {
                af[g][s] = *(const bf16x8*)aP[g][s];
                bf[g][s] = *(const bf16x8*)bP[g][s];
            }
#pragma unroll
        for (int s = 0; s < 2; s++)
#pragma unroll
            for (int mg = 0; mg < 2; mg++)
#pragma unroll
                for (int ng = 0; ng < 2; ng++)
                    acc[mg][ng] = __builtin_amdgcn_mfma_f32_32x32x16_bf16(
                        af[mg][s], bf[ng][s], acc[mg][ng], 0, 0, 0);
    }

    // C/D layout (verified): col = lane&31, row = (reg&3) + 8*(reg>>2) + 4*(lane>>5)
    if (MODE == 0) {
#pragma unroll
        for (int mg = 0; mg < 2; mg++) {
#pragma unroll
            for (int ng = 0; ng < 2; ng++) {
                int gcol = bn + wn + ng * 32 + n32;
#pragma unroll
                for (int reg = 0; reg < 16; reg++) {
                    int grow = bm + wm + mg * 32 + (reg & 3) + 8 * (reg >> 2) + 4 * khalf;
                    ((float*)Cv)[(size_t)grow * N + gcol] = acc[mg][ng][reg];
                }
            }
        }
    } else {
        const int colbase = bn + wn;  // 64-aligned: one head's d-range per wave
        if (bn < H + 512) {
            // Q or K with fused RoPE (block-uniform branch; per-wave stores coalesced)
#pragma unroll
            for (int mg = 0; mg < 2; mg++) {
#pragma unroll
                for (int reg = 0; reg < 16; reg++) {
                    int grow = bm + wm + mg * 32 + (reg & 3) + 8 * (reg >> 2) + 4 * khalf;
                    int s = grow & 1023, b = grow >> 10;
                    float x0 = acc[mg][0][reg], x1 = acc[mg][1][reg];
                    float c0  = cosb[s * 64 + n32],      sn0 = sinb[s * 64 + n32];
                    float c1  = cosb[s * 64 + 32 + n32], sn1 = sinb[s * 64 + 32 + n32];
                    unsigned short o0 = f2b(x0 * c0 - x1 * sn0);
                    unsigned short o1 = f2b(x1 * c1 + x0 * sn1);
                    unsigned short* dp;
                    if (bn < H) {
                        dp = qa + (size_t)(b * 64 + (colbase >> 6)) * (S * D) + s * 64 + n32;
                    } else {
                        dp = ka + (size_t)(b * 8 + ((colbase - H) >> 6)) * (S * D) + s * 64 + n32;
                    }
                    dp[0] = o0; dp[32] = o1;
                }
            }
        } else {
            // V block: cooperative 128x128 transpose via LDS, stores coalesced along s
            __syncthreads();   // everyone done with As/Bs (aliased by sh)
#pragma unroll
            for (int mg = 0; mg < 2; mg++)
#pragma unroll
                for (int ng = 0; ng < 2; ng++)
#pragma unroll
                    for (int reg = 0; reg < 16; reg++) {
                        int cl = wn + ng * 32 + n32;   // local col = V's d-within-block
                        int rl = wm + mg * 32 + (reg & 3) + 8 * (reg >> 2) + 4 * khalf;
                        sh[cl * 136 + rl] = f2b(acc[mg][ng][reg]);
                    }
            __syncthreads();
            {
                const int bb = bm >> 10, s0 = bm & 1023;
                const int kv0 = (bn - (H + 512)) >> 6;
                const int cl = tid >> 1, shalf = (tid & 1) * 64;
                const int kv = kv0 + (cl >> 6), dd = cl & 63;
                unsigned short* dstp = vt + (size_t)(bb * 8 + kv) * (D * S)
                                          + (size_t)dd * S + s0 + shalf;
                const unsigned short* srcp = sh + cl * 136 + shalf;
#pragma unroll
                for (int j = 0; j < 8; j++)
                    *(short8*)(dstp + j * 8) = *(const short8*)(srcp + j * 8);
            }
        }
    }
}

// ---------------- Flash attention, pair-balanced, 2 query heads per block ----------------
// K/V read direct from global (L2-hot), no per-K-tile barriers; waves desynchronized;
// setprio(1) wraps MFMA clusters.
__global__ __launch_bounds__(256) void attn_kernel(
    const unsigned short* __restrict__ qa, const unsigned short* __restrict__ ka,
    const unsigned short* __restrict__ vt, unsigned short* __restrict__ out) {
    __shared__ unsigned short Ps[4 * 16 * 72];   // wave-private P round-trip only
    const int p = blockIdx.x;
    const int yy = blockIdx.y;
    const int b = yy >> 5, kvh = (yy >> 2) & 7, gp = yy & 3;
    const int h0 = b * 64 + kvh * 8 + gp * 2;
    const int tid = threadIdx.x, w = tid >> 6, lane = tid & 63;
    const int col = lane & 15, quad = lane >> 4;
    const unsigned short* Kg = ka + (size_t)(b * NKV + kvh) * (S * D);
    const unsigned short* Vg = vt + (size_t)(b * NKV + kvh) * (D * S);
    float4v zero4 = {0.f, 0.f, 0.f, 0.f};
    const float SC2 = 0.125f * 1.44269504089f;  // fold 1/sqrt(D) and log2(e): exp2 domain

#pragma unroll
    for (int part = 0; part < 2; part++) {
        const int qt = part ? (15 - p) : p;
        const int qb = qt * 64;

        bf16x8 aq[2][2];
#pragma unroll
        for (int hd = 0; hd < 2; hd++)
#pragma unroll
            for (int c = 0; c < 2; c++)
                aq[hd][c] = *(const bf16x8*)&qa[(size_t)(h0 + hd) * (S * D) + (size_t)qb * D
                                               + (w * 16 + col) * 64 + c * 32 + quad * 8];

        float m_run[2][4], l_run[2][4];
        float4v o_acc[2][4];
#pragma unroll
        for (int hd = 0; hd < 2; hd++) {
#pragma unroll
            for (int r = 0; r < 4; r++) { m_run[hd][r] = -1e30f; l_run[hd][r] = 0.f; }
#pragma unroll
            for (int dg = 0; dg < 4; dg++) o_acc[hd][dg] = zero4;
        }

        for (int kt = 0; kt <= qt; kt++) {
            const int kb = kt * 64;
            bf16x8 bk[4][2], bv[4][2];
#pragma unroll
            for (int n16 = 0; n16 < 4; n16++) {
                const unsigned short* kr = &Kg[(size_t)(kb + n16 * 16 + col) * 64 + quad * 8];
                bk[n16][0] = *(const bf16x8*)kr;
                bk[n16][1] = *(const bf16x8*)(kr + 32);
            }
#pragma unroll
            for (int dg = 0; dg < 4; dg++) {
                const unsigned short* vr = &Vg[(size_t)(dg * 16 + col) * S + kb + quad * 8];
                bv[dg][0] = *(const bf16x8*)vr;
                bv[dg][1] = *(const bf16x8*)(vr + 32);
            }

#pragma unroll
            for (int hd = 0; hd < 2; hd++) {
                float4v sc[4];
                __builtin_amdgcn_s_setprio(1);
#pragma unroll
                for (int n16 = 0; n16 < 4; n16++) {
                    float4v a = __builtin_amdgcn_mfma_f32_16x16x32_bf16(aq[hd][0], bk[n16][0], zero4, 0, 0, 0);
                    sc[n16] = __builtin_amdgcn_mfma_f32_16x16x32_bf16(aq[hd][1], bk[n16][1], a, 0, 0, 0);
                }
                __builtin_amdgcn_s_setprio(0);
#pragma unroll
                for (int n16 = 0; n16 < 4; n16++) {
                    int key = kb + n16 * 16 + col;
#pragma unroll
                    for (int r = 0; r < 4; r++) {
                        int qrow = qb + w * 16 + quad * 4 + r;
                        float sv = sc[n16][r] * SC2;
                        sc[n16][r] = (key <= qrow) ? sv : -1e30f;
                    }
                }
#pragma unroll
                for (int r = 0; r < 4; r++) {
                    float mx = fmaxf(fmaxf(sc[0][r], sc[1][r]), fmaxf(sc[2][r], sc[3][r]));
#pragma unroll
                    for (int off = 1; off < 16; off <<= 1) mx = fmaxf(mx, __shfl_xor(mx, off));
                    float mnew = fmaxf(m_run[hd][r], mx);
                    float alpha = __builtin_amdgcn_exp2f(m_run[hd][r] - mnew);
                    float rsum = 0.f;
#pragma unroll
                    for (int n16 = 0; n16 < 4; n16++) {
                        float pr = __builtin_amdgcn_exp2f(sc[n16][r] - mnew);
                        sc[n16][r] = pr;
                        rsum += pr;
                    }
#pragma unroll
                    for (int off = 1; off < 16; off <<= 1) rsum += __shfl_xor(rsum, off);
                    l_run[hd][r] = l_run[hd][r] * alpha + rsum;
                    m_run[hd][r] = mnew;
#pragma unroll
                    for (int dg = 0; dg < 4; dg++) o_acc[hd][dg][r] *= alpha;
                }
#pragma unroll
                for (int n16 = 0; n16 < 4; n16++)
#pragma unroll
                    for (int r = 0; r < 4; r++)
                        Ps[w * 1152 + (quad * 4 + r) * 72 + n16 * 16 + col] = f2b(sc[n16][r]);
                bf16x8 ap[2];
#pragma unroll
                for (int c = 0; c < 2; c++)
                    ap[c] = *(const bf16x8*)&Ps[w * 1152 + col * 72 + c * 32 + quad * 8];
                __builtin_amdgcn_s_setprio(1);
#pragma unroll
                for (int dg = 0; dg < 4; dg++) {
                    float4v t = __builtin_amdgcn_mfma_f32_16x16x32_bf16(ap[0], bv[dg][0], o_acc[hd][dg], 0, 0, 0);
                    o_acc[hd][dg] = __builtin_amdgcn_mfma_f32_16x16x32_bf16(ap[1], bv[dg][1], t, 0, 0, 0);
                }
                __builtin_amdgcn_s_setprio(0);
            }
        }
#pragma unroll
        for (int hd = 0; hd < 2; hd++) {
            const int hcol = ((h0 + hd) & 63) * 64;
#pragma unroll
            for (int r = 0; r < 4; r++) {
                float inv = 1.f / l_run[hd][r];
                int grow = b * S + qb + w * 16 + quad * 4 + r;
#pragma unroll
                for (int dg = 0; dg < 4; dg++)
                    out[(size_t)grow * H + hcol + dg * 16 + col] = f2b(o_acc[hd][dg][r] * inv);
            }
        }
    }
}

extern "C" void kernel_launch(void* const* d_in, const int* in_sizes, int n_in,
                              void* d_out, int out_size, void* d_ws, size_t ws_size,
                              hipStream_t stream) {
    const float* hs   = (const float*)d_in[0];
    // d_in[1] alibi, d_in[2] attention_mask: unused by reference (zeros)
    const float* cosb = (const float*)d_in[3];
    const float* sinb = (const float*)d_in[4];
    const float* wq   = (const float*)d_in[5];
    const float* wk   = (const float*)d_in[6];
    const float* wv   = (const float*)d_in[7];
    const float* wd   = (const float*)d_in[8];

    char* p = (char*)d_ws;
    auto alloc = [&](size_t bytes) { char* r = p; p += (bytes + 255) & ~(size_t)255; return r; };
    unsigned short* wqkv_b = (unsigned short*)alloc((size_t)NQKV * H * 2);
    unsigned short* wd_b   = (unsigned short*)alloc((size_t)H * H * 2);
    unsigned short* qa     = (unsigned short*)alloc((size_t)BB * NH * S * D * 2);
    unsigned short* ka     = (unsigned short*)alloc((size_t)BB * NKV * S * D * 2);
    unsigned short* vt     = (unsigned short*)alloc((size_t)BB * NKV * S * D * 2);
    unsigned short* hs_b   = (unsigned short*)alloc((size_t)MROWS * H * 2);
    unsigned short* ao     = hs_b;  // alias: hs_b consumed by GEMM1 before attn writes ao

    cvt_all<<<4096, 256, 0, stream>>>(hs, wq, wk, wv, wd, hs_b, wqkv_b, wd_b);

    // GEMM1 with fused RoPE+scatter epilogue (writes qa/ka/vt directly)
    gemm_nt<1><<<dim3(NQKV / 128, MROWS / 128), 256, 0, stream>>>(
        hs_b, wqkv_b, nullptr, MROWS, NQKV, H, cosb, sinb, qa, ka, vt);
    attn_kernel<<<dim3(8, 64), 256, 0, stream>>>(qa, ka, vt, ao);
    gemm_nt<0><<<dim3(H / 128, MROWS / 128), 256, 0, stream>>>(
        ao, wd_b, d_out, MROWS, H, H, nullptr, nullptr, nullptr, nullptr, nullptr);
}